// Round 1
// baseline (5167.299 us; speedup 1.0000x reference)
//
#include <hip/hip_runtime.h>
#include <math.h>

// ---------------------------------------------------------------------------
// ConvLSTM stack: 4 x (ConvLSTM2D + MaxPool(1,2,2)) -> Flatten -> Dense -> Softmax
// Layout everywhere: channels-last, (B, T, H, W, C) contiguous (matches ref).
//
// Layer dims:
//  L1: Cin=3,  F=4,  128->126 -> pool 63
//  L2: Cin=4,  F=8,   63-> 61 -> pool 31
//  L3: Cin=8,  F=12,  31-> 29 -> pool 15
//  L4: Cin=12, F=16,  15-> 13 -> pool 7
// FLAT = 24*7*7*16 = 18816, K = 50 classes, B = 32, T = 24.
// ---------------------------------------------------------------------------

static __device__ __forceinline__ float hsig(float x) {
    return fminf(fmaxf(fmaf(0.2f, x, 0.5f), 0.0f), 1.0f);
}

// One thread per (b, y, x, fo). Computes the fused gate pre-activation:
//   g = conv_valid(P_t, Wx) + conv_same(h_{t-1}, Wh) + bias
// then the LSTM cell update. h_t is written into hs[:, t]; h_{t-1} is read
// from hs[:, t-1] (t==0: zeros, handled by skipping — never reads poisoned ws).
template<int CIN, int F, int HIN, int WIN>
__global__ __launch_bounds__(256)
void lstm_step_k(const float* __restrict__ P,    // (B,T,HIN,WIN,CIN)
                 const float* __restrict__ Wx,   // (3,3,CIN,4F)
                 const float* __restrict__ Wh,   // (3,3,F,4F)
                 const float* __restrict__ bias, // (4F)
                 float* __restrict__ hs,         // (B,T,HO,WO,F)
                 float* __restrict__ cbuf,       // (B,HO,WO,F)
                 int t)
{
    constexpr int B = 32, T = 24;
    constexpr int HO = HIN - 2, WO = WIN - 2;
    constexpr int G = 4 * F;
    constexpr int TOTAL = B * HO * WO * F;

    int idx = blockIdx.x * blockDim.x + threadIdx.x;
    if (idx >= TOTAL) return;
    int fo = idx % F;
    int xx = (idx / F) % WO;
    int yy = (idx / (F * WO)) % HO;
    int b  = idx / (F * WO * HO);

    float g0 = bias[0 * F + fo];   // i
    float g1 = bias[1 * F + fo];   // f
    float g2 = bias[2 * F + fo];   // c~
    float g3 = bias[3 * F + fo];   // o

    // Input convolution (VALID): window P_t[yy..yy+2, xx..xx+2]
    const float* Pt = P + (size_t)(b * T + t) * HIN * WIN * CIN;
    #pragma unroll
    for (int ky = 0; ky < 3; ++ky) {
        #pragma unroll
        for (int kx = 0; kx < 3; ++kx) {
            const float* prow = Pt + ((yy + ky) * WIN + (xx + kx)) * CIN;
            const float* wrow = Wx + (size_t)((ky * 3 + kx) * CIN) * G + fo;
            #pragma unroll
            for (int ci = 0; ci < CIN; ++ci) {
                float v = prow[ci];
                const float* w = wrow + ci * G;
                g0 = fmaf(v, w[0],     g0);
                g1 = fmaf(v, w[F],     g1);
                g2 = fmaf(v, w[2 * F], g2);
                g3 = fmaf(v, w[3 * F], g3);
            }
        }
    }

    // Recurrent convolution (SAME, zero-pad): window h_{t-1}[yy-1..yy+1, ...]
    if (t > 0) {
        const float* Hp = hs + (size_t)(b * T + (t - 1)) * HO * WO * F;
        #pragma unroll
        for (int ky = 0; ky < 3; ++ky) {
            int hy = yy + ky - 1;
            if (hy < 0 || hy >= HO) continue;
            #pragma unroll
            for (int kx = 0; kx < 3; ++kx) {
                int hx = xx + kx - 1;
                if (hx < 0 || hx >= WO) continue;
                const float* hrow = Hp + (hy * WO + hx) * F;
                const float* wrow = Wh + (size_t)((ky * 3 + kx) * F) * G + fo;
                #pragma unroll
                for (int ci = 0; ci < F; ++ci) {
                    float v = hrow[ci];
                    const float* w = wrow + ci * G;
                    g0 = fmaf(v, w[0],     g0);
                    g1 = fmaf(v, w[F],     g1);
                    g2 = fmaf(v, w[2 * F], g2);
                    g3 = fmaf(v, w[3 * F], g3);
                }
            }
        }
    }

    float ig = hsig(g0), fg = hsig(g1), cc = tanhf(g2), og = hsig(g3);
    size_t cidx = ((size_t)(b * HO + yy) * WO + xx) * F + fo;
    float cold = (t > 0) ? cbuf[cidx] : 0.0f;   // t==0: c0 = 0, never read ws
    float cnew = fmaf(fg, cold, ig * cc);
    cbuf[cidx] = cnew;
    hs[(size_t)(b * T + t) * HO * WO * F + ((size_t)yy * WO + xx) * F + fo]
        = og * tanhf(cnew);
}

// MaxPool (1,2,2) stride (1,2,2) SAME over (N=B*T, H, W, C).
__global__ __launch_bounds__(256)
void pool_k(const float* __restrict__ in, float* __restrict__ out,
            int NT, int H, int W, int C, int HP, int WP)
{
    int idx = blockIdx.x * blockDim.x + threadIdx.x;
    int total = NT * HP * WP * C;
    if (idx >= total) return;
    int c  = idx % C;
    int xo = (idx / C) % WP;
    int yo = (idx / (C * WP)) % HP;
    int n  = idx / (C * WP * HP);
    int y0 = 2 * yo, x0 = 2 * xo;
    const float* base = in + (size_t)n * H * W * C + c;
    float m = base[(y0 * W + x0) * C];
    if (x0 + 1 < W) m = fmaxf(m, base[(y0 * W + x0 + 1) * C]);
    if (y0 + 1 < H) {
        m = fmaxf(m, base[((y0 + 1) * W + x0) * C]);
        if (x0 + 1 < W) m = fmaxf(m, base[((y0 + 1) * W + x0 + 1) * C]);
    }
    out[idx] = m;
}

// Dense (18816 x 50) + softmax. One block per batch row, 256 threads = 4 waves.
// lane (0..63) owns class k=lane (k<50): Wd reads are 50-consecutive-float
// coalesced; the i-range is split across the 4 waves, LDS-reduced, then wave 0
// does a 64-lane shuffle softmax.
__global__ __launch_bounds__(256)
void dense_softmax_k(const float* __restrict__ X,   // (B, FLAT)
                     const float* __restrict__ Wd,  // (FLAT, K)
                     const float* __restrict__ bd,  // (K)
                     float* __restrict__ out)       // (B, K)
{
    constexpr int FLAT = 18816, K = 50;
    int b    = blockIdx.x;
    int tid  = threadIdx.x;
    int lane = tid & 63;
    int wv   = tid >> 6;
    const float* x = X + (size_t)b * FLAT;

    float acc = 0.0f;
    if (lane < K) {
        int i0 = wv * (FLAT / 4), i1 = i0 + FLAT / 4;
        for (int i = i0; i < i1; ++i)
            acc = fmaf(x[i], Wd[(size_t)i * K + lane], acc);
    }
    __shared__ float red[256];
    red[tid] = acc;
    __syncthreads();
    if (tid < 64) {
        float v = red[tid] + red[tid + 64] + red[tid + 128] + red[tid + 192];
        v = (lane < K) ? v + bd[lane] : -INFINITY;
        float m = v;
        #pragma unroll
        for (int off = 32; off > 0; off >>= 1)
            m = fmaxf(m, __shfl_xor(m, off));
        float e = (lane < K) ? __expf(v - m) : 0.0f;
        float s = e;
        #pragma unroll
        for (int off = 32; off > 0; off >>= 1)
            s += __shfl_xor(s, off);
        if (lane < K) out[(size_t)b * K + lane] = e / s;
    }
}

template<int CIN, int F, int HIN, int WIN>
static void run_layer(const float* P, const float* Wx, const float* Wh,
                      const float* bias, float* hs, float* cbuf, float* pooled,
                      hipStream_t stream)
{
    constexpr int B = 32, T = 24;
    constexpr int HO = HIN - 2, WO = WIN - 2;
    constexpr int HP = (HO + 1) / 2, WP = (WO + 1) / 2;
    constexpr int TOTAL = B * HO * WO * F;
    int blocks = (TOTAL + 255) / 256;
    for (int t = 0; t < T; ++t)
        lstm_step_k<CIN, F, HIN, WIN><<<blocks, 256, 0, stream>>>(
            P, Wx, Wh, bias, hs, cbuf, t);
    int ptotal = B * T * HP * WP * F;
    pool_k<<<(ptotal + 255) / 256, 256, 0, stream>>>(
        hs, pooled, B * T, HO, WO, F, HP, WP);
}

extern "C" void kernel_launch(void* const* d_in, const int* in_sizes, int n_in,
                              void* d_out, int out_size, void* d_ws, size_t ws_size,
                              hipStream_t stream)
{
    const float* x   = (const float*)d_in[0];
    const float* Wx1 = (const float*)d_in[1];
    const float* Wh1 = (const float*)d_in[2];
    const float* b1  = (const float*)d_in[3];
    const float* Wx2 = (const float*)d_in[4];
    const float* Wh2 = (const float*)d_in[5];
    const float* b2  = (const float*)d_in[6];
    const float* Wx3 = (const float*)d_in[7];
    const float* Wh3 = (const float*)d_in[8];
    const float* b3  = (const float*)d_in[9];
    const float* Wx4 = (const float*)d_in[10];
    const float* Wh4 = (const float*)d_in[11];
    const float* b4  = (const float*)d_in[12];
    const float* Wd  = (const float*)d_in[13];
    const float* bd  = (const float*)d_in[14];
    float* out = (float*)d_out;

    // Workspace carve-up (floats). Peak need ~276 MB.
    float* ws    = (float*)d_ws;
    float* hs    = ws;                    // max 32*24*126*126*4  = 48,771,072
    float* poolA = hs + 48771072;         // max 32*24*63*63*4    = 12,192,768
    float* poolB = poolA + 12192768;      // max 32*24*31*31*8    =  5,903,616
    float* cbuf  = poolB + 5903616;       // max 32*126*126*4     =  2,032,128

    run_layer< 3,  4, 128, 128>(x,     Wx1, Wh1, b1, hs, cbuf, poolA, stream);
    run_layer< 4,  8,  63,  63>(poolA, Wx2, Wh2, b2, hs, cbuf, poolB, stream);
    run_layer< 8, 12,  31,  31>(poolB, Wx3, Wh3, b3, hs, cbuf, poolA, stream);
    run_layer<12, 16,  15,  15>(poolA, Wx4, Wh4, b4, hs, cbuf, poolB, stream);

    // poolB now holds (B, T*7*7*16) = (32, 18816) row-major == Keras Flatten.
    dense_softmax_k<<<32, 256, 0, stream>>>(poolB, Wd, bd, out);
}

// Round 2
// 2126.598 us; speedup vs baseline: 2.4298x; 2.4298x over previous
//
#include <hip/hip_runtime.h>
#include <math.h>

// ---------------------------------------------------------------------------
// ConvLSTM stack: 4 x (ConvLSTM2D + MaxPool(1,2,2)) -> Flatten -> Dense -> Softmax
// Layout everywhere: channels-last, (B, T, H, W, C) contiguous (matches ref).
//
//  L1: Cin=3,  F=4,  128->126 -> pool 63
//  L2: Cin=4,  F=8,   63-> 61 -> pool 31
//  L3: Cin=8,  F=12,  31-> 29 -> pool 15
//  L4: Cin=12, F=16,  15-> 13 -> pool 7
// FLAT = 24*7*7*16 = 18816, K = 50 classes, B = 32, T = 24.
//
// LSTM-step decomposition (round 2): block = 256 threads = 4 waves.
//   wave w owns GATE TYPE w (i/f/c/o = contiguous F-slices of the 4F axis),
//   its 64 lanes own 64 consecutive pixels. All weight indices are then
//   wave-uniform -> scalar (s_load) weights, SGPR operand in v_fma.
//   Gates are exchanged through LDS; update stage remaps to (pixel,fo).
// ---------------------------------------------------------------------------

static __device__ __forceinline__ float hsig(float x) {
    return fminf(fmaxf(fmaf(0.2f, x, 0.5f), 0.0f), 1.0f);
}

template<int CIN, int F, int HIN, int WIN>
__global__ __launch_bounds__(256)
void lstm_step_k(const float* __restrict__ P,    // (B,T,HIN,WIN,CIN)
                 const float* __restrict__ Wx,   // (3,3,CIN,4F)
                 const float* __restrict__ Wh,   // (3,3,F,4F)
                 const float* __restrict__ bias, // (4F)
                 float* __restrict__ hs,         // (B,T,HO,WO,F)
                 float* __restrict__ cbuf,       // (B,HO,WO,F) == pix*F+fo
                 int t)
{
    constexpr int B = 32, T = 24;
    constexpr int HO = HIN - 2, WO = WIN - 2;
    constexpr int G = 4 * F;
    constexpr int NPIX = B * HO * WO;

    const int tid  = threadIdx.x;
    const int lane = tid & 63;
    // wave-uniform gate slice index (forces SGPR -> scalar weight loads)
    const int w = __builtin_amdgcn_readfirstlane(tid >> 6);

    const int pix   = blockIdx.x * 64 + lane;
    const bool valid = (pix < NPIX);
    const int pp = valid ? pix : 0;
    const int xx = pp % WO;
    const int yy = (pp / WO) % HO;
    const int b  = pp / (WO * HO);

    // slice bases: weight index = (kk*C + ci)*G + w*F + f  -> wave-uniform
    const float* wxs = Wx + w * F;
    const float* whs = Wh + w * F;

    float acc[F];
    #pragma unroll
    for (int f = 0; f < F; ++f) acc[f] = bias[w * F + f];   // scalar load

    // ---- input convolution (VALID): window P_t[yy..yy+2, xx..xx+2] ----
    const float* Pt = P + (size_t)(b * T + t) * HIN * WIN * CIN;
    #pragma unroll
    for (int ky = 0; ky < 3; ++ky) {
        #pragma unroll
        for (int kx = 0; kx < 3; ++kx) {
            const float* prow = Pt + ((yy + ky) * WIN + (xx + kx)) * CIN;
            #pragma unroll
            for (int ci = 0; ci < CIN; ++ci) {
                const float v = prow[ci];
                const float* wr = wxs + (size_t)((ky * 3 + kx) * CIN + ci) * G;
                #pragma unroll
                for (int f = 0; f < F; ++f)
                    acc[f] = fmaf(v, wr[f], acc[f]);        // SGPR weight
            }
        }
    }

    // ---- recurrent convolution (SAME, zero-pad) on h_{t-1} ----
    if (t > 0) {
        const float* Hp = hs + (size_t)(b * T + (t - 1)) * HO * WO * F;
        #pragma unroll
        for (int ky = 0; ky < 3; ++ky) {
            const int hy = yy + ky - 1;
            if (hy < 0 || hy >= HO) continue;
            #pragma unroll
            for (int kx = 0; kx < 3; ++kx) {
                const int hx = xx + kx - 1;
                if (hx < 0 || hx >= WO) continue;
                const float* hrow = Hp + (size_t)(hy * WO + hx) * F;
                #pragma unroll
                for (int ci = 0; ci < F; ++ci) {
                    const float v = hrow[ci];
                    const float* wr = whs + (size_t)((ky * 3 + kx) * F + ci) * G;
                    #pragma unroll
                    for (int f = 0; f < F; ++f)
                        acc[f] = fmaf(v, wr[f], acc[f]);    // SGPR weight
                }
            }
        }
    }

    // ---- exchange gates through LDS, then cell update ----
    __shared__ float gb[4][64 * F];   // [gate][pixel_local*F + fo]
    #pragma unroll
    for (int f = 0; f < F; ++f) gb[w][lane * F + f] = acc[f];
    __syncthreads();

    #pragma unroll
    for (int r = 0; r < F / 4; ++r) {           // 64*F items, 256 threads
        const int it  = r * 256 + tid;
        const int pl  = it / F;
        const int fo  = it % F;
        const int pix2 = blockIdx.x * 64 + pl;
        if (pix2 < NPIX) {
            const float gi = gb[0][it];
            const float gf = gb[1][it];
            const float gc = gb[2][it];
            const float go = gb[3][it];
            const float ig = hsig(gi), fg = hsig(gf);
            const float cc = tanhf(gc), og = hsig(go);
            const size_t cix = (size_t)pix2 * F + fo;
            const float cold = (t > 0) ? cbuf[cix] : 0.0f;  // t==0: never read ws
            const float cn = fmaf(fg, cold, ig * cc);
            cbuf[cix] = cn;
            const int xx2 = pix2 % WO;
            const int yy2 = (pix2 / WO) % HO;
            const int b2  = pix2 / (WO * HO);
            hs[(size_t)(b2 * T + t) * HO * WO * F
               + (size_t)(yy2 * WO + xx2) * F + fo] = og * tanhf(cn);
        }
    }
}

// MaxPool (1,2,2) stride (1,2,2) SAME over (N=B*T, H, W, C).
__global__ __launch_bounds__(256)
void pool_k(const float* __restrict__ in, float* __restrict__ out,
            int NT, int H, int W, int C, int HP, int WP)
{
    int idx = blockIdx.x * blockDim.x + threadIdx.x;
    int total = NT * HP * WP * C;
    if (idx >= total) return;
    int c  = idx % C;
    int xo = (idx / C) % WP;
    int yo = (idx / (C * WP)) % HP;
    int n  = idx / (C * WP * HP);
    int y0 = 2 * yo, x0 = 2 * xo;
    const float* base = in + (size_t)n * H * W * C + c;
    float m = base[(y0 * W + x0) * C];
    if (x0 + 1 < W) m = fmaxf(m, base[(y0 * W + x0 + 1) * C]);
    if (y0 + 1 < H) {
        m = fmaxf(m, base[((y0 + 1) * W + x0) * C]);
        if (x0 + 1 < W) m = fmaxf(m, base[((y0 + 1) * W + x0 + 1) * C]);
    }
    out[idx] = m;
}

// ---- Dense (18816 x 50) stage 1: partial sums over FLAT chunks. ----
// grid (B, NC); block 256 = 4 waves; wave covers 392 i's; lane<50 owns class.
// x[i] is wave-uniform -> scalar load; Wd row read is 50-lane coalesced.
__global__ __launch_bounds__(256)
void dense_partial_k(const float* __restrict__ X,   // (B, FLAT)
                     const float* __restrict__ Wd,  // (FLAT, K)
                     float* __restrict__ part)      // (B, NC, K)
{
    constexpr int FLAT = 18816, K = 50, NC = 12, CHUNK = FLAT / NC; // 1568
    const int b = blockIdx.x, ch = blockIdx.y;
    const int tid = threadIdx.x, lane = tid & 63, wv = tid >> 6;
    const float* x = X + (size_t)b * FLAT;
    const int i0 = ch * CHUNK + wv * (CHUNK / 4);   // 392 per wave
    float a0 = 0.f, a1 = 0.f, a2 = 0.f, a3 = 0.f;
    if (lane < K) {
        for (int i = i0; i < i0 + CHUNK / 4; i += 4) {
            a0 = fmaf(x[i + 0], Wd[(size_t)(i + 0) * K + lane], a0);
            a1 = fmaf(x[i + 1], Wd[(size_t)(i + 1) * K + lane], a1);
            a2 = fmaf(x[i + 2], Wd[(size_t)(i + 2) * K + lane], a2);
            a3 = fmaf(x[i + 3], Wd[(size_t)(i + 3) * K + lane], a3);
        }
    }
    __shared__ float red[256];
    red[tid] = (a0 + a1) + (a2 + a3);
    __syncthreads();
    if (tid < 64 && lane < K)
        part[((size_t)b * NC + ch) * K + lane]
            = red[tid] + red[tid + 64] + red[tid + 128] + red[tid + 192];
}

// ---- Dense stage 2: reduce NC partials + bias, softmax. 1 block/row. ----
__global__ __launch_bounds__(64)
void dense_finish_k(const float* __restrict__ part, const float* __restrict__ bd,
                    float* __restrict__ out)
{
    constexpr int K = 50, NC = 12;
    const int b = blockIdx.x, lane = threadIdx.x;
    float v = -INFINITY;
    if (lane < K) {
        v = bd[lane];
        #pragma unroll
        for (int c = 0; c < NC; ++c)
            v += part[((size_t)b * NC + c) * K + lane];
    }
    float m = v;
    #pragma unroll
    for (int off = 32; off > 0; off >>= 1)
        m = fmaxf(m, __shfl_xor(m, off));
    float e = (lane < K) ? __expf(v - m) : 0.0f;
    float s = e;
    #pragma unroll
    for (int off = 32; off > 0; off >>= 1)
        s += __shfl_xor(s, off);
    if (lane < K) out[(size_t)b * K + lane] = e / s;
}

template<int CIN, int F, int HIN, int WIN>
static void run_layer(const float* P, const float* Wx, const float* Wh,
                      const float* bias, float* hs, float* cbuf, float* pooled,
                      hipStream_t stream)
{
    constexpr int B = 32, T = 24;
    constexpr int HO = HIN - 2, WO = WIN - 2;
    constexpr int HP = (HO + 1) / 2, WP = (WO + 1) / 2;
    constexpr int NPIX = B * HO * WO;
    const int blocks = (NPIX + 63) / 64;           // 64 pixels per block
    for (int t = 0; t < T; ++t)
        lstm_step_k<CIN, F, HIN, WIN><<<blocks, 256, 0, stream>>>(
            P, Wx, Wh, bias, hs, cbuf, t);
    const int ptotal = B * T * HP * WP * F;
    pool_k<<<(ptotal + 255) / 256, 256, 0, stream>>>(
        hs, pooled, B * T, HO, WO, F, HP, WP);
}

extern "C" void kernel_launch(void* const* d_in, const int* in_sizes, int n_in,
                              void* d_out, int out_size, void* d_ws, size_t ws_size,
                              hipStream_t stream)
{
    const float* x   = (const float*)d_in[0];
    const float* Wx1 = (const float*)d_in[1];
    const float* Wh1 = (const float*)d_in[2];
    const float* b1  = (const float*)d_in[3];
    const float* Wx2 = (const float*)d_in[4];
    const float* Wh2 = (const float*)d_in[5];
    const float* b2  = (const float*)d_in[6];
    const float* Wx3 = (const float*)d_in[7];
    const float* Wh3 = (const float*)d_in[8];
    const float* b3  = (const float*)d_in[9];
    const float* Wx4 = (const float*)d_in[10];
    const float* Wh4 = (const float*)d_in[11];
    const float* b4  = (const float*)d_in[12];
    const float* Wd  = (const float*)d_in[13];
    const float* bd  = (const float*)d_in[14];
    float* out = (float*)d_out;

    // Workspace carve-up (floats). Peak ~276 MB.
    float* ws    = (float*)d_ws;
    float* hs    = ws;                    // max 32*24*126*126*4  = 48,771,072
    float* poolA = hs + 48771072;         // max 32*24*63*63*4    = 12,192,768
    float* poolB = poolA + 12192768;      // max 32*24*31*31*8    =  5,903,616
    float* cbuf  = poolB + 5903616;       // max 32*126*126*4     =  2,032,128
    float* dpart = cbuf + 2032128;        // 32*12*50             =     19,200

    run_layer< 3,  4, 128, 128>(x,     Wx1, Wh1, b1, hs, cbuf, poolA, stream);
    run_layer< 4,  8,  63,  63>(poolA, Wx2, Wh2, b2, hs, cbuf, poolB, stream);
    run_layer< 8, 12,  31,  31>(poolB, Wx3, Wh3, b3, hs, cbuf, poolA, stream);
    run_layer<12, 16,  15,  15>(poolA, Wx4, Wh4, b4, hs, cbuf, poolB, stream);

    // poolB holds (B, T*7*7*16) = (32, 18816) row-major == Keras Flatten.
    dense_partial_k<<<dim3(32, 12), 256, 0, stream>>>(poolB, Wd, dpart);
    dense_finish_k<<<32, 64, 0, stream>>>(dpart, bd, out);
}

// Round 3
// 1810.177 us; speedup vs baseline: 2.8546x; 1.1748x over previous
//
#include <hip/hip_runtime.h>
#include <math.h>

// ---------------------------------------------------------------------------
// ConvLSTM stack: 4 x (ConvLSTM2D + MaxPool(1,2,2)) -> Flatten -> Dense -> Softmax
// Layout everywhere: channels-last, (B,T,H,W,C) contiguous (matches ref).
//
//  L1: Cin=3,  F=4,  128->126 -> pool 63
//  L2: Cin=4,  F=8,   63-> 61 -> pool 31
//  L3: Cin=8,  F=12,  31-> 29 -> pool 15
//  L4: Cin=12, F=16,  15-> 13 -> pool 7
// FLAT = 24*7*7*16 = 18816, K = 50, B = 32, T = 24.
//
// Round-3 structure:
//  - xconv_k  : batched input conv over all (b,t) for L2/L3/L4 (bias folded),
//               gate-split waves -> all weight loads wave-uniform (SGPR).
//  - lstm_fused4_k (L1): fused input+recurrent; ONE wave computes ALL 4 gates
//               for its 64 pixels (gate = uniform loop index -> SGPR weights),
//               so activation windows are loaded once, epilogue in-register.
//  - rstep4_k (L2): recurrent-only, gates merged per wave (same trick).
//  - rstep1_k (L3/L4): recurrent-only, gate-split (parallelism matters more
//               than load reuse at 26912/5408 pixels), LDS gate exchange.
//  - fast tanh via v_exp/v_rcp (|err| ~1e-6, exact at +-inf).
// ---------------------------------------------------------------------------

static __device__ __forceinline__ float hsig(float x) {
    return fminf(fmaxf(fmaf(0.2f, x, 0.5f), 0.0f), 1.0f);
}
static __device__ __forceinline__ float ftanh(float x) {
    // tanh(x) = 1 - 2/(e^{2x}+1);  e^{2x} = exp2(x * 2*log2(e))
    float e = __builtin_amdgcn_exp2f(x * 2.88539008177792681f);
    return 1.0f - 2.0f * __builtin_amdgcn_rcpf(e + 1.0f);
}

// ---- batched input convolution (VALID) + bias, over NT=768 images ----
// grid: NQ/64 blocks of 256; wave w = gate w (uniform -> scalar weights);
// lanes own 64 consecutive output pixels. xg layout: (B,T,HO,WO,4F).
template<int CIN, int F, int HIN, int WIN>
__global__ __launch_bounds__(256)
void xconv_k(const float* __restrict__ P,    // (B,T,HIN,WIN,CIN)
             const float* __restrict__ Wx,   // (3,3,CIN,4F)
             const float* __restrict__ bias, // (4F)
             float* __restrict__ xg)         // (B,T,HO,WO,4F)
{
    constexpr int HO = HIN - 2, WO = WIN - 2, G = 4 * F;
    constexpr int NT = 32 * 24;
    constexpr int NQ = NT * HO * WO;
    const int lane = threadIdx.x & 63;
    const int w = __builtin_amdgcn_readfirstlane(threadIdx.x >> 6);
    const int q = blockIdx.x * 64 + lane;
    if (q >= NQ) return;
    const int s  = q % (HO * WO);
    const int n  = q / (HO * WO);
    const int xx = s % WO, yy = s / WO;

    float acc[F];
    #pragma unroll
    for (int f = 0; f < F; ++f) acc[f] = bias[w * F + f];

    const float* Pn = P + (size_t)n * HIN * WIN * CIN;
    #pragma unroll
    for (int ky = 0; ky < 3; ++ky) {
        #pragma unroll
        for (int kx = 0; kx < 3; ++kx) {
            const float* prow = Pn + ((yy + ky) * WIN + (xx + kx)) * CIN;
            #pragma unroll
            for (int ci = 0; ci < CIN; ++ci) {
                const float v = prow[ci];
                const float* wr = Wx + (size_t)((ky * 3 + kx) * CIN + ci) * G + w * F;
                #pragma unroll
                for (int f = 0; f < F; ++f)
                    acc[f] = fmaf(v, wr[f], acc[f]);
            }
        }
    }
    float* o = xg + (size_t)q * G + w * F;      // 16B aligned (F%4==0)
    #pragma unroll
    for (int j = 0; j < F / 4; ++j)
        reinterpret_cast<float4*>(o)[j] = make_float4(
            acc[4 * j], acc[4 * j + 1], acc[4 * j + 2], acc[4 * j + 3]);
}

// ---- L1 fused step: gates merged per wave, input conv + recurrent ----
template<int CIN, int F, int HIN, int WIN>
__global__ __launch_bounds__(256)
void lstm_fused4_k(const float* __restrict__ P,    // (B,T,HIN,WIN,CIN)
                   const float* __restrict__ Wx,   // (3,3,CIN,4F)
                   const float* __restrict__ Wh,   // (3,3,F,4F)
                   const float* __restrict__ bias, // (4F)
                   float* __restrict__ hs,         // (B,T,HO,WO,F)
                   float* __restrict__ cbuf,       // (B,HO,WO,F)
                   int t)
{
    constexpr int B = 32, T = 24, HO = HIN - 2, WO = WIN - 2, G = 4 * F;
    constexpr int NPIX = B * HO * WO;
    const int pix = blockIdx.x * 256 + threadIdx.x;
    if (pix >= NPIX) return;
    const int s  = pix % (HO * WO);
    const int b  = pix / (HO * WO);
    const int xx = s % WO, yy = s / WO;

    float acc[4][F];
    #pragma unroll
    for (int g = 0; g < 4; ++g)
        #pragma unroll
        for (int f = 0; f < F; ++f) acc[g][f] = bias[g * F + f];

    const float* Pt = P + (size_t)(b * T + t) * HIN * WIN * CIN;
    #pragma unroll
    for (int ky = 0; ky < 3; ++ky) {
        #pragma unroll
        for (int kx = 0; kx < 3; ++kx) {
            const float* prow = Pt + ((yy + ky) * WIN + (xx + kx)) * CIN;
            #pragma unroll
            for (int ci = 0; ci < CIN; ++ci) {
                const float v = prow[ci];
                const float* wr = Wx + (size_t)((ky * 3 + kx) * CIN + ci) * G;
                #pragma unroll
                for (int g = 0; g < 4; ++g)
                    #pragma unroll
                    for (int f = 0; f < F; ++f)
                        acc[g][f] = fmaf(v, wr[g * F + f], acc[g][f]);
            }
        }
    }

    if (t > 0) {
        const float* Hp = hs + (size_t)(b * T + (t - 1)) * HO * WO * F;
        #pragma unroll
        for (int ky = 0; ky < 3; ++ky) {
            const int hy = yy + ky - 1;
            if (hy < 0 || hy >= HO) continue;
            #pragma unroll
            for (int kx = 0; kx < 3; ++kx) {
                const int hx = xx + kx - 1;
                if (hx < 0 || hx >= WO) continue;
                const float4* h4 = reinterpret_cast<const float4*>(
                    Hp + (size_t)(hy * WO + hx) * F);
                float hv[F];
                #pragma unroll
                for (int j = 0; j < F / 4; ++j) {
                    float4 v4 = h4[j];
                    hv[4*j] = v4.x; hv[4*j+1] = v4.y; hv[4*j+2] = v4.z; hv[4*j+3] = v4.w;
                }
                #pragma unroll
                for (int ci = 0; ci < F; ++ci) {
                    const float v = hv[ci];
                    const float* wr = Wh + (size_t)((ky * 3 + kx) * F + ci) * G;
                    #pragma unroll
                    for (int g = 0; g < 4; ++g)
                        #pragma unroll
                        for (int f = 0; f < F; ++f)
                            acc[g][f] = fmaf(v, wr[g * F + f], acc[g][f]);
                }
            }
        }
    }

    // in-register cell update (this lane owns all 4 gates of its pixel)
    float cn[F], ho[F];
    float* cp = cbuf + (size_t)pix * F;
    #pragma unroll
    for (int j = 0; j < F / 4; ++j) {
        float4 c4 = (t > 0) ? reinterpret_cast<float4*>(cp)[j]
                            : make_float4(0.f, 0.f, 0.f, 0.f);
        float cold[4] = {c4.x, c4.y, c4.z, c4.w};
        #pragma unroll
        for (int u = 0; u < 4; ++u) {
            const int f = 4 * j + u;
            const float ig = hsig(acc[0][f]), fg = hsig(acc[1][f]);
            const float cc = ftanh(acc[2][f]), og = hsig(acc[3][f]);
            cn[f] = fmaf(fg, cold[u], ig * cc);
            ho[f] = og * ftanh(cn[f]);
        }
        reinterpret_cast<float4*>(cp)[j] =
            make_float4(cn[4*j], cn[4*j+1], cn[4*j+2], cn[4*j+3]);
    }
    float* hp = hs + ((size_t)(b * T + t) * HO * WO + s) * F;
    #pragma unroll
    for (int j = 0; j < F / 4; ++j)
        reinterpret_cast<float4*>(hp)[j] =
            make_float4(ho[4*j], ho[4*j+1], ho[4*j+2], ho[4*j+3]);
}

// ---- recurrent-only step, gates merged per wave (L2) ----
template<int F, int HO, int WO>
__global__ __launch_bounds__(256)
void rstep4_k(const float* __restrict__ xg,   // (B,T,HO,WO,4F) bias folded
              const float* __restrict__ Wh,   // (3,3,F,4F)
              float* __restrict__ hs,         // (B,T,HO,WO,F)
              float* __restrict__ cbuf,       // (B,HO,WO,F)
              int t)
{
    constexpr int B = 32, T = 24, G = 4 * F;
    constexpr int NPIX = B * HO * WO;
    const int pix = blockIdx.x * 256 + threadIdx.x;
    if (pix >= NPIX) return;
    const int s  = pix % (HO * WO);
    const int b  = pix / (HO * WO);
    const int xx = s % WO, yy = s / WO;

    float acc[4][F];
    const float* xp = xg + ((size_t)(b * T + t) * HO * WO + s) * G;
    #pragma unroll
    for (int g = 0; g < 4; ++g)
        #pragma unroll
        for (int j = 0; j < F / 4; ++j) {
            float4 v4 = reinterpret_cast<const float4*>(xp)[g * (F / 4) + j];
            acc[g][4*j] = v4.x; acc[g][4*j+1] = v4.y;
            acc[g][4*j+2] = v4.z; acc[g][4*j+3] = v4.w;
        }

    if (t > 0) {
        const float* Hp = hs + (size_t)(b * T + (t - 1)) * HO * WO * F;
        #pragma unroll
        for (int ky = 0; ky < 3; ++ky) {
            const int hy = yy + ky - 1;
            if (hy < 0 || hy >= HO) continue;
            #pragma unroll
            for (int kx = 0; kx < 3; ++kx) {
                const int hx = xx + kx - 1;
                if (hx < 0 || hx >= WO) continue;
                const float4* h4 = reinterpret_cast<const float4*>(
                    Hp + (size_t)(hy * WO + hx) * F);
                float hv[F];
                #pragma unroll
                for (int j = 0; j < F / 4; ++j) {
                    float4 v4 = h4[j];
                    hv[4*j] = v4.x; hv[4*j+1] = v4.y; hv[4*j+2] = v4.z; hv[4*j+3] = v4.w;
                }
                #pragma unroll
                for (int ci = 0; ci < F; ++ci) {
                    const float v = hv[ci];
                    const float* wr = Wh + (size_t)((ky * 3 + kx) * F + ci) * G;
                    #pragma unroll
                    for (int g = 0; g < 4; ++g)
                        #pragma unroll
                        for (int f = 0; f < F; ++f)
                            acc[g][f] = fmaf(v, wr[g * F + f], acc[g][f]);
                }
            }
        }
    }

    float cn[F], ho[F];
    float* cp = cbuf + (size_t)pix * F;
    #pragma unroll
    for (int j = 0; j < F / 4; ++j) {
        float4 c4 = (t > 0) ? reinterpret_cast<float4*>(cp)[j]
                            : make_float4(0.f, 0.f, 0.f, 0.f);
        float cold[4] = {c4.x, c4.y, c4.z, c4.w};
        #pragma unroll
        for (int u = 0; u < 4; ++u) {
            const int f = 4 * j + u;
            const float ig = hsig(acc[0][f]), fg = hsig(acc[1][f]);
            const float cc = ftanh(acc[2][f]), og = hsig(acc[3][f]);
            cn[f] = fmaf(fg, cold[u], ig * cc);
            ho[f] = og * ftanh(cn[f]);
        }
        reinterpret_cast<float4*>(cp)[j] =
            make_float4(cn[4*j], cn[4*j+1], cn[4*j+2], cn[4*j+3]);
    }
    float* hp = hs + ((size_t)(b * T + t) * HO * WO + s) * F;
    #pragma unroll
    for (int j = 0; j < F / 4; ++j)
        reinterpret_cast<float4*>(hp)[j] =
            make_float4(ho[4*j], ho[4*j+1], ho[4*j+2], ho[4*j+3]);
}

// ---- recurrent-only step, gate-split waves (L3/L4: parallelism-starved) ----
template<int F, int HO, int WO>
__global__ __launch_bounds__(256)
void rstep1_k(const float* __restrict__ xg, const float* __restrict__ Wh,
              float* __restrict__ hs, float* __restrict__ cbuf, int t)
{
    constexpr int B = 32, T = 24, G = 4 * F;
    constexpr int NPIX = B * HO * WO;
    const int tid = threadIdx.x, lane = tid & 63;
    const int w = __builtin_amdgcn_readfirstlane(tid >> 6);
    const int pix = blockIdx.x * 64 + lane;
    const bool valid = (pix < NPIX);
    const int pp = valid ? pix : NPIX - 1;
    const int s  = pp % (HO * WO);
    const int b  = pp / (HO * WO);
    const int xx = s % WO, yy = s / WO;

    float acc[F];
    const float* xp = xg + ((size_t)(b * T + t) * HO * WO + s) * G + w * F;
    #pragma unroll
    for (int j = 0; j < F / 4; ++j) {
        float4 v4 = reinterpret_cast<const float4*>(xp)[j];
        acc[4*j] = v4.x; acc[4*j+1] = v4.y; acc[4*j+2] = v4.z; acc[4*j+3] = v4.w;
    }

    if (t > 0) {
        const float* Hp = hs + (size_t)(b * T + (t - 1)) * HO * WO * F;
        #pragma unroll
        for (int ky = 0; ky < 3; ++ky) {
            const int hy = yy + ky - 1;
            if (hy < 0 || hy >= HO) continue;
            #pragma unroll
            for (int kx = 0; kx < 3; ++kx) {
                const int hx = xx + kx - 1;
                if (hx < 0 || hx >= WO) continue;
                const float4* h4 = reinterpret_cast<const float4*>(
                    Hp + (size_t)(hy * WO + hx) * F);
                float hv[F];
                #pragma unroll
                for (int j = 0; j < F / 4; ++j) {
                    float4 v4 = h4[j];
                    hv[4*j] = v4.x; hv[4*j+1] = v4.y; hv[4*j+2] = v4.z; hv[4*j+3] = v4.w;
                }
                #pragma unroll
                for (int ci = 0; ci < F; ++ci) {
                    const float v = hv[ci];
                    const float* wr = Wh + (size_t)((ky * 3 + kx) * F + ci) * G + w * F;
                    #pragma unroll
                    for (int f = 0; f < F; ++f)
                        acc[f] = fmaf(v, wr[f], acc[f]);
                }
            }
        }
    }

    __shared__ float gb[4][64 * F];
    #pragma unroll
    for (int f = 0; f < F; ++f) gb[w][lane * F + f] = acc[f];
    __syncthreads();

    #pragma unroll
    for (int r = 0; r < F / 4; ++r) {          // 64*F items / 256 threads
        const int it = r * 256 + tid;
        const int pl = it / F;
        const int fo = it % F;
        const int pix2 = blockIdx.x * 64 + pl;
        if (pix2 < NPIX) {
            const float ig = hsig(gb[0][it]), fg = hsig(gb[1][it]);
            const float cc = ftanh(gb[2][it]), og = hsig(gb[3][it]);
            const size_t cix = (size_t)pix2 * F + fo;
            const float cold = (t > 0) ? cbuf[cix] : 0.0f;
            const float cnw = fmaf(fg, cold, ig * cc);
            cbuf[cix] = cnw;
            const int s2 = pix2 % (HO * WO);
            const int b2 = pix2 / (HO * WO);
            hs[((size_t)(b2 * T + t) * HO * WO + s2) * F + fo] = og * ftanh(cnw);
        }
    }
}

// MaxPool (1,2,2) stride (1,2,2) SAME over (N=B*T, H, W, C).
__global__ __launch_bounds__(256)
void pool_k(const float* __restrict__ in, float* __restrict__ out,
            int NT, int H, int W, int C, int HP, int WP)
{
    int idx = blockIdx.x * blockDim.x + threadIdx.x;
    int total = NT * HP * WP * C;
    if (idx >= total) return;
    int c  = idx % C;
    int xo = (idx / C) % WP;
    int yo = (idx / (C * WP)) % HP;
    int n  = idx / (C * WP * HP);
    int y0 = 2 * yo, x0 = 2 * xo;
    const float* base = in + (size_t)n * H * W * C + c;
    float m = base[(y0 * W + x0) * C];
    if (x0 + 1 < W) m = fmaxf(m, base[(y0 * W + x0 + 1) * C]);
    if (y0 + 1 < H) {
        m = fmaxf(m, base[((y0 + 1) * W + x0) * C]);
        if (x0 + 1 < W) m = fmaxf(m, base[((y0 + 1) * W + x0 + 1) * C]);
    }
    out[idx] = m;
}

// ---- Dense (18816 x 50) stage 1: partial sums over FLAT chunks ----
__global__ __launch_bounds__(256)
void dense_partial_k(const float* __restrict__ X, const float* __restrict__ Wd,
                     float* __restrict__ part)
{
    constexpr int FLAT = 18816, K = 50, NC = 12, CHUNK = FLAT / NC; // 1568
    const int b = blockIdx.x, ch = blockIdx.y;
    const int tid = threadIdx.x, lane = tid & 63, wv = tid >> 6;
    const float* x = X + (size_t)b * FLAT;
    const int i0 = ch * CHUNK + wv * (CHUNK / 4);
    float a0 = 0.f, a1 = 0.f, a2 = 0.f, a3 = 0.f;
    if (lane < K) {
        for (int i = i0; i < i0 + CHUNK / 4; i += 4) {
            a0 = fmaf(x[i + 0], Wd[(size_t)(i + 0) * K + lane], a0);
            a1 = fmaf(x[i + 1], Wd[(size_t)(i + 1) * K + lane], a1);
            a2 = fmaf(x[i + 2], Wd[(size_t)(i + 2) * K + lane], a2);
            a3 = fmaf(x[i + 3], Wd[(size_t)(i + 3) * K + lane], a3);
        }
    }
    __shared__ float red[256];
    red[tid] = (a0 + a1) + (a2 + a3);
    __syncthreads();
    if (tid < 64 && lane < K)
        part[((size_t)b * NC + ch) * K + lane]
            = red[tid] + red[tid + 64] + red[tid + 128] + red[tid + 192];
}

__global__ __launch_bounds__(64)
void dense_finish_k(const float* __restrict__ part, const float* __restrict__ bd,
                    float* __restrict__ out)
{
    constexpr int K = 50, NC = 12;
    const int b = blockIdx.x, lane = threadIdx.x;
    float v = -INFINITY;
    if (lane < K) {
        v = bd[lane];
        #pragma unroll
        for (int c = 0; c < NC; ++c)
            v += part[((size_t)b * NC + c) * K + lane];
    }
    float m = v;
    #pragma unroll
    for (int off = 32; off > 0; off >>= 1) m = fmaxf(m, __shfl_xor(m, off));
    float e = (lane < K) ? __expf(v - m) : 0.0f;
    float s = e;
    #pragma unroll
    for (int off = 32; off > 0; off >>= 1) s += __shfl_xor(s, off);
    if (lane < K) out[(size_t)b * K + lane] = e / s;
}

extern "C" void kernel_launch(void* const* d_in, const int* in_sizes, int n_in,
                              void* d_out, int out_size, void* d_ws, size_t ws_size,
                              hipStream_t stream)
{
    const float* x   = (const float*)d_in[0];
    const float* Wx1 = (const float*)d_in[1];
    const float* Wh1 = (const float*)d_in[2];
    const float* b1  = (const float*)d_in[3];
    const float* Wx2 = (const float*)d_in[4];
    const float* Wh2 = (const float*)d_in[5];
    const float* b2  = (const float*)d_in[6];
    const float* Wx3 = (const float*)d_in[7];
    const float* Wh3 = (const float*)d_in[8];
    const float* b3  = (const float*)d_in[9];
    const float* Wx4 = (const float*)d_in[10];
    const float* Wh4 = (const float*)d_in[11];
    const float* b4  = (const float*)d_in[12];
    const float* Wd  = (const float*)d_in[13];
    const float* bd  = (const float*)d_in[14];
    float* out = (float*)d_out;

    // ---- workspace layout (floats); ws_size ≈ 576 MiB = 150.99M floats ----
    // hs lives at 0 (per-layer size); xg_L is placed just past that layer's
    // live hs, inside [0, 114,309,120). Audited: no phase overlap.
    float* ws    = (float*)d_ws;
    float* hs    = ws;
    float* xg2   = ws + 22861824;          // hs2 = 768*3721*8
    float* xg3   = ws + 7750656;           // hs3 = 768*841*12
    float* xg4   = ws + 2076672;           // hs4 = 768*169*16
    float* pool1 = ws + 114309120;         // 12,192,768  (xg2 ends exactly here)
    float* pool2 = ws + 126501888;         //  5,904,384
    float* cbuf  = ws + 132406272;         //  2,032,128
    float* dpart = ws + 134438400;         //     19,200  -> total 134,457,600

    // ---- L1 (fused input conv, gates merged per wave) ----
    for (int t = 0; t < 24; ++t)
        lstm_fused4_k<3, 4, 128, 128><<<1985, 256, 0, stream>>>(
            x, Wx1, Wh1, b1, hs, cbuf, t);
    pool_k<<<(12192768 + 255) / 256, 256, 0, stream>>>(
        hs, pool1, 768, 126, 126, 4, 63, 63);

    // ---- L2 ----
    xconv_k<4, 8, 63, 63><<<44652, 256, 0, stream>>>(pool1, Wx2, b2, xg2);
    for (int t = 0; t < 24; ++t)
        rstep4_k<8, 61, 61><<<466, 256, 0, stream>>>(xg2, Wh2, hs, cbuf, t);
    pool_k<<<(5904384 + 255) / 256, 256, 0, stream>>>(
        hs, pool2, 768, 61, 61, 8, 31, 31);

    // ---- L3 ----
    xconv_k<8, 12, 31, 31><<<10092, 256, 0, stream>>>(pool2, Wx3, b3, xg3);
    for (int t = 0; t < 24; ++t)
        rstep1_k<12, 29, 29><<<421, 256, 0, stream>>>(xg3, Wh3, hs, cbuf, t);
    pool_k<<<(2073600 + 255) / 256, 256, 0, stream>>>(
        hs, pool1, 768, 29, 29, 12, 15, 15);

    // ---- L4 ----
    xconv_k<12, 16, 15, 15><<<2028, 256, 0, stream>>>(pool1, Wx4, b4, xg4);
    for (int t = 0; t < 24; ++t)
        rstep1_k<16, 13, 13><<<85, 256, 0, stream>>>(xg4, Wh4, hs, cbuf, t);
    pool_k<<<(602112 + 255) / 256, 256, 0, stream>>>(
        hs, pool2, 768, 13, 13, 16, 7, 7);

    // pool2 = (B, 18816) row-major == Keras Flatten
    dense_partial_k<<<dim3(32, 12), 256, 0, stream>>>(pool2, Wd, dpart);
    dense_finish_k<<<32, 64, 0, stream>>>(dpart, bd, out);
}